// Round 4
// baseline (285.877 us; speedup 1.0000x reference)
//
#include <hip/hip_runtime.h>

#define I_DIM 17
#define H_DIM 128
#define T_DIM 19
#define B_DIM 32768
#define M_ROWS 32
#define TILES 2
#define NTHR 512
#define GRID (B_DIM / (M_ROWS * TILES)) /* 512 */
#define XI 323

typedef __bf16 bf16x8 __attribute__((ext_vector_type(8)));
typedef float f32x4 __attribute__((ext_vector_type(4)));

union FragU { bf16x8 v; unsigned short s[8]; uint4 u; };

// LDS: WiF 32 frags | WoF 8 frags | Hl 2 x [32][256B] dbuf | Xl 2 x [32][80B] dbuf
#define OFF_WIF 0
#define OFF_WOF 32768
#define OFF_H   40960
#define OFF_X   57344
#define LDS_TOT 62464

#define K1 1.4426950408889634f
#define K2 2.8853900817779268f

__device__ __forceinline__ unsigned short f2bf(float f) {
    union { float f; unsigned u; } x; x.f = f;
    return (unsigned short)((x.u + 0x8000u) >> 16);
}

// One timestep. T_: runtime t value; P_: compile-time (t&1) so all LDS buffer
// selects fold into ds_read/ds_write imm offsets.
// reads:  h_{t-1} from Hbuf[1-P_], x_t from Xbuf[P_]
// writes: h_t to Hbuf[P_], x_{t+1} to Xbuf[1-P_], y_{t-1} to global
#define STEP(T_, P_) do {                                                        \
    float xr1 = 0.f, xr2 = 0.f;                                                  \
    if ((T_) + 1 < T_DIM) {                                                      \
        xr1 = xp1[((T_) + 1) * I_DIM];                                           \
        if (xv2) xr2 = xp2[((T_) + 1) * I_DIM];                                  \
    }                                                                            \
    f32x4 acc[2][4];                                                             \
    _Pragma("unroll") for (int mtl = 0; mtl < 2; ++mtl)                          \
        _Pragma("unroll") for (int g = 0; g < 4; ++g)                            \
            acc[mtl][g] = (f32x4){bias[g], bias[g], bias[g], bias[g]};           \
    /* x-projection (K=32 zero-padded) */                                        \
    _Pragma("unroll") for (int mtl = 0; mtl < 2; ++mtl) {                        \
        bf16x8 a = *(const bf16x8*)(smem + vax + (OFF_X + (P_)*2560 + mtl*1280));\
        _Pragma("unroll") for (int g = 0; g < 4; ++g) {                          \
            bf16x8 b = *(const bf16x8*)(smem + vwi + (OFF_WIF + g*1024));        \
            acc[mtl][g] = __builtin_amdgcn_mfma_f32_16x16x32_bf16(a, b, acc[mtl][g], 0, 0, 0); \
        }                                                                        \
    }                                                                            \
    /* recurrent: h_{t-1} @ W_hh^T, B-frags in registers */                      \
    _Pragma("unroll") for (int kk = 0; kk < 4; ++kk)                             \
        _Pragma("unroll") for (int mtl = 0; mtl < 2; ++mtl) {                    \
            bf16x8 a = *(const bf16x8*)(smem + vkk[kk] + (OFF_H + (1-(P_))*8192 + mtl*4096)); \
            _Pragma("unroll") for (int g = 0; g < 4; ++g)                        \
                acc[mtl][g] = __builtin_amdgcn_mfma_f32_16x16x32_bf16(a, whh[kk][g], acc[mtl][g], 0, 0, 0); \
        }                                                                        \
    /* y_{t-1} = h_{t-1} @ W_out^T (waves 0..3) */                               \
    if ((T_) > 0 && w < 4) {                                                     \
        f32x4 ya = {0.f, 0.f, 0.f, 0.f};                                         \
        _Pragma("unroll") for (int kk = 0; kk < 4; ++kk) {                       \
            bf16x8 a = *(const bf16x8*)(smem + vkk[kk] + (OFF_H + (1-(P_))*8192 + ymt*4096)); \
            bf16x8 b = *(const bf16x8*)(smem + vwo + (OFF_WOF + kk*1024));       \
            ya = __builtin_amdgcn_mfma_f32_16x16x32_bf16(a, b, ya, 0, 0, 0);     \
        }                                                                        \
        if (yok) {                                                               \
            _Pragma("unroll") for (int r = 0; r < 4; ++r)                        \
                youtp[r * (T_DIM * I_DIM)] = ya[r] + ybo;                        \
        }                                                                        \
        youtp += I_DIM;                                                          \
    }                                                                            \
    /* elementwise (5 exp2 + 2 rcp per cell), write h_t */                       \
    _Pragma("unroll") for (int mtl = 0; mtl < 2; ++mtl)                          \
        _Pragma("unroll") for (int r = 0; r < 4; ++r) {                          \
            float ig = acc[mtl][0][r], fg = acc[mtl][1][r];                      \
            float gg = acc[mtl][2][r], og = acc[mtl][3][r];                      \
            float ui = __builtin_amdgcn_exp2f(-K1 * ig);                         \
            float uf = __builtin_amdgcn_exp2f(-K1 * fg);                         \
            float vg = __builtin_amdgcn_exp2f(-K2 * gg);                         \
            float uo = __builtin_amdgcn_exp2f(-K1 * og);                         \
            float A_ = 1.f + ui, F_ = 1.f + uf, G_ = 1.f + vg;                   \
            float AG = A_ * G_;                                                  \
            float c = (cst[mtl*4+r] * AG + (1.f - vg) * F_) * __builtin_amdgcn_rcpf(F_ * AG); \
            cst[mtl*4+r] = c;                                                    \
            float vc = __builtin_amdgcn_exp2f(-K2 * c);                          \
            float h = (1.f - vc) * __builtin_amdgcn_rcpf((1.f + uo) * (1.f + vc)); \
            *(unsigned short*)(smem + vwr[r] + (OFF_H + (P_)*8192 + mtl*4096)) = f2bf(h); \
        }                                                                        \
    if ((T_) + 1 < T_DIM) {                                                      \
        *(unsigned short*)(smem + xlo1 + (OFF_X + (1-(P_))*2560)) = f2bf(xr1);   \
        if (xv2) *(unsigned short*)(smem + xlo2 + (OFF_X + (1-(P_))*2560)) = f2bf(xr2); \
    }                                                                            \
    __syncthreads();                                                             \
} while (0)

__global__ __launch_bounds__(NTHR, 4) void flowlstm(
    const float* __restrict__ x, const float* __restrict__ W_ih,
    const float* __restrict__ W_hh, const float* __restrict__ b_ih,
    const float* __restrict__ b_hh, const float* __restrict__ W_out,
    const float* __restrict__ b_out, float* __restrict__ out)
{
    __shared__ __align__(16) unsigned char smem[LDS_TOT];
    const int tid = threadIdx.x;
    const int w = tid >> 6, lane = tid & 63, l15 = lane & 15, q = lane >> 4;
    const int wg = w & 3, half = w >> 2;

    // ---- stage W_ih fragments (32 frags, K padded 17->32) ----
    #pragma unroll
    for (int i = 0; i < 4; ++i) {
        int s = tid + i * NTHR;
        int ln = s & 63, f = s >> 6;
        int g = f & 3, hf = (f >> 2) & 1, wgs = f >> 3;
        int n = g * H_DIM + wgs * 32 + hf * 16 + (ln & 15);
        int kb = (ln >> 4) * 8;
        FragU fu;
        #pragma unroll
        for (int e = 0; e < 8; ++e)
            fu.s[e] = (kb + e < I_DIM) ? f2bf(W_ih[n * I_DIM + kb + e]) : (unsigned short)0;
        *(uint4*)(smem + OFF_WIF + f * 1024 + ln * 16) = fu.u;
    }
    // ---- stage W_out fragments (8 frags, N padded 17->32) ----
    {
        int ln = tid & 63, f = tid >> 6;
        int kk = f & 3, nt = f >> 2;
        int o = nt * 16 + (ln & 15);
        int kb = kk * 32 + (ln >> 4) * 8;
        FragU fu;
        #pragma unroll
        for (int e = 0; e < 8; ++e)
            fu.s[e] = (o < I_DIM) ? f2bf(W_out[o * H_DIM + kb + e]) : (unsigned short)0;
        *(uint4*)(smem + OFF_WOF + tid * 16) = fu.u;
    }
    // ---- zero both X buffers (K-pad stays zero forever) ----
    #pragma unroll
    for (int i = 0; i < 3; ++i) {
        int e = tid + i * NTHR;
        if (e < 1280) ((unsigned*)(smem + OFF_X))[e] = 0u;
    }
    // ---- W_hh fragments in registers (compiler -> AGPR): 16 frags ----
    bf16x8 whh[4][4];
    #pragma unroll
    for (int kk = 0; kk < 4; ++kk)
        #pragma unroll
        for (int g = 0; g < 4; ++g) {
            int n = g * H_DIM + wg * 32 + half * 16 + l15;
            const float* s = W_hh + n * H_DIM + kk * 32 + q * 8;
            FragU fu;
            #pragma unroll
            for (int e = 0; e < 8; ++e) fu.s[e] = f2bf(s[e]);
            whh[kk][g] = fu.v;
        }
    float bias[4];
    #pragma unroll
    for (int g = 0; g < 4; ++g) {
        int col = g * H_DIM + wg * 32 + half * 16 + l15;
        bias[g] = b_ih[col] + b_hh[col];
    }
    // ---- t-invariant LDS vaddrs (buffer/mtl selects go in imm offsets) ----
    const unsigned xr7 = (unsigned)((l15 & 7) << 4);
    unsigned vkk[4], vwr[4];
    #pragma unroll
    for (int kk = 0; kk < 4; ++kk)
        vkk[kk] = (unsigned)(l15 * 256 + ((kk * 64 + q * 16) ^ xr7));
    const int colh2 = (wg * 32 + half * 16 + l15) * 2;
    #pragma unroll
    for (int r = 0; r < 4; ++r) {
        int rr = q * 4 + r;
        vwr[r] = (unsigned)(rr * 256 + (colh2 ^ ((rr & 7) << 4)));
    }
    const unsigned vax = (unsigned)(l15 * 80 + q * 16);
    const unsigned vwi = (unsigned)((wg * 2 + half) * 4096 + lane * 16);
    const int ymt = w >> 1, ynt = w & 1;
    const unsigned vwo = (unsigned)(ynt * 4096 + lane * 16);
    const int ycol = ynt * 16 + l15;
    const bool yok = (w < 4) && (ycol < I_DIM);
    const float ybo = b_out[ycol < I_DIM ? ycol : 16];

    // ---- x staging map (512 threads cover 32*17=544 elems in <=2) ----
    const int  xrow1 = tid / I_DIM, xk1 = tid - xrow1 * I_DIM;
    const bool xv2 = tid < (M_ROWS * I_DIM - NTHR);   // tid < 32
    const int  t2 = tid + NTHR;
    const int  xrow2 = t2 / I_DIM, xk2 = t2 - xrow2 * I_DIM;
    const unsigned xlo1 = (unsigned)(xrow1 * 80 + xk1 * 2);
    const unsigned xlo2 = (unsigned)(xrow2 * 80 + xk2 * 2);

    #pragma unroll 1
    for (int tile = 0; tile < TILES; ++tile) {
        const int b0 = blockIdx.x * (M_ROWS * TILES) + tile * M_ROWS;
        const float* xp1 = x + (size_t)(b0 + xrow1) * XI + xk1;
        const float* xp2 = x + (size_t)(b0 + xrow2) * XI + xk2;
        float* youtp = out + (size_t)(b0 + ymt * 16 + q * 4) * (T_DIM * I_DIM) + ycol;
        float cst[8];
        #pragma unroll
        for (int i = 0; i < 8; ++i) cst[i] = 0.f;
        // zero Hbuf[1] (h_{-1} = 0); last read of it was before prev tile's last barrier
        #pragma unroll
        for (int i = 0; i < 4; ++i)
            ((unsigned*)(smem + OFF_H + 8192))[tid + i * NTHR] = 0u;
        // stage x_0 into Xbuf[0]
        *(unsigned short*)(smem + xlo1 + OFF_X) = f2bf(xp1[0]);
        if (xv2) *(unsigned short*)(smem + xlo2 + OFF_X) = f2bf(xp2[0]);
        __syncthreads();

        #pragma unroll 1
        for (int t = 0; t < T_DIM - 1; t += 2) {
            STEP(t, 0);
            STEP(t + 1, 1);
        }
        STEP(T_DIM - 1, 0);   // t = 18

        // ---- epilogue: y_{18} from Hbuf[0] ----
        if (w < 4) {
            f32x4 ya = {0.f, 0.f, 0.f, 0.f};
            #pragma unroll
            for (int kk = 0; kk < 4; ++kk) {
                bf16x8 a = *(const bf16x8*)(smem + vkk[kk] + (OFF_H + ymt * 4096));
                bf16x8 b = *(const bf16x8*)(smem + vwo + (OFF_WOF + kk * 1024));
                ya = __builtin_amdgcn_mfma_f32_16x16x32_bf16(a, b, ya, 0, 0, 0);
            }
            if (yok) {
                #pragma unroll
                for (int r = 0; r < 4; ++r)
                    youtp[r * (T_DIM * I_DIM)] = ya[r] + ybo;
            }
        }
        __syncthreads();   // protect Hbuf[1] re-zero / x restage of next tile
    }
}

extern "C" void kernel_launch(void* const* d_in, const int* in_sizes, int n_in,
                              void* d_out, int out_size, void* d_ws, size_t ws_size,
                              hipStream_t stream) {
    const float* x     = (const float*)d_in[0];
    const float* W_ih  = (const float*)d_in[1];
    const float* W_hh  = (const float*)d_in[2];
    const float* b_ih  = (const float*)d_in[3];
    const float* b_hh  = (const float*)d_in[4];
    const float* W_out = (const float*)d_in[5];
    const float* b_out = (const float*)d_in[6];
    float* out = (float*)d_out;

    dim3 grid(GRID), block(NTHR);
    flowlstm<<<grid, block, 0, stream>>>(x, W_ih, W_hh, b_ih, b_hh, W_out, b_out, out);
}